// Round 6
// baseline (867.566 us; speedup 1.0000x reference)
//
#include <hip/hip_runtime.h>
#include <hip/hip_bf16.h>
#include <math.h>

#define N_NODES 400000
#define N_EDGES 2400000
#define NPG 40
#define N_GRAPHS 10000
#define IN_F 30
#define H1 30
#define H2 10
#define OUTF 4
#define SCAN_NB 10      // ceil(10000/1024)
#define GPB 2           // graphs per block in fused kernel
#define NBLK (N_GRAPHS / GPB)
#define CAP 768         // LDS edge-id staging cap (per-block edges ~ Poisson(480), 5sigma ~ 590)

// ---------------- K1: per-graph edge histogram ----------------
__global__ void hist_kernel(const int4* __restrict__ dst4, int* __restrict__ gsum) {
    int i = blockIdx.x * blockDim.x + threadIdx.x;
    int stride = gridDim.x * blockDim.x;
    const int n4 = N_EDGES / 4;
    for (; i < n4; i += stride) {
        int4 d = dst4[i];
        atomicAdd(&gsum[d.x / NPG], 1);
        atomicAdd(&gsum[d.y / NPG], 1);
        atomicAdd(&gsum[d.z / NPG], 1);
        atomicAdd(&gsum[d.w / NPG], 1);
    }
}

// ---------------- exclusive scan of gsum -> bin_start (+sentinel), gcursor ----------------
__global__ void scan1(const int* __restrict__ v_in, int* __restrict__ ex_out,
                      int* __restrict__ blk_sums, int n) {
    __shared__ int s[256];
    int t = threadIdx.x;
    int base = blockIdx.x * 1024 + t * 4;
    int v[4];
    #pragma unroll
    for (int k = 0; k < 4; k++) v[k] = (base + k < n) ? v_in[base + k] : 0;
    int tsum = v[0] + v[1] + v[2] + v[3];
    s[t] = tsum;
    __syncthreads();
    for (int o = 1; o < 256; o <<= 1) {
        int y = (t >= o) ? s[t - o] : 0;
        __syncthreads();
        s[t] += y;
        __syncthreads();
    }
    int run = s[t] - tsum;
    #pragma unroll
    for (int k = 0; k < 4; k++) {
        if (base + k < n) ex_out[base + k] = run;
        run += v[k];
    }
    if (t == 255) blk_sums[blockIdx.x] = s[255];
}

__global__ void scan2(const int* __restrict__ blk_sums, int* __restrict__ blk_off, int nb) {
    if (threadIdx.x == 0) {
        int run = 0;
        for (int i = 0; i < nb; i++) { blk_off[i] = run; run += blk_sums[i]; }
    }
}

__global__ void scan3(int* __restrict__ bin_start, int* __restrict__ gcursor,
                      const int* __restrict__ blk_off, const int* __restrict__ gsum, int n) {
    int t = threadIdx.x;
    int off = blk_off[blockIdx.x];
    int base = blockIdx.x * 1024 + t * 4;
    #pragma unroll
    for (int k = 0; k < 4; k++) {
        int i = base + k;
        if (i < n) {
            int r = bin_start[i] + off;
            bin_start[i] = r;
            gcursor[i] = r;
            if (i == n - 1) bin_start[n] = r + gsum[i];  // sentinel = N_EDGES
        }
    }
}

// ---------------- K2: bin edges by dst graph; also out-degree histogram ----------------
// packed word: (src << 8) | ((g & 3) << 6) | dst_local   (src < 2^19)
__global__ void bin_fill(const int4* __restrict__ src4, const int4* __restrict__ dst4,
                         int* __restrict__ gcursor, unsigned* __restrict__ binned,
                         int* __restrict__ deg_out) {
    int i = blockIdx.x * blockDim.x + threadIdx.x;
    int stride = gridDim.x * blockDim.x;
    const int n4 = N_EDGES / 4;
    for (; i < n4; i += stride) {
        int4 s = src4[i];
        int4 d = dst4[i];
        #pragma unroll
        for (int k = 0; k < 4; k++) {
            int dd = (k == 0) ? d.x : (k == 1) ? d.y : (k == 2) ? d.z : d.w;
            int ss = (k == 0) ? s.x : (k == 1) ? s.y : (k == 2) ? s.z : s.w;
            int g = dd / NPG;
            int dl = dd - g * NPG;
            int pos = atomicAdd(&gcursor[g], 1);
            binned[pos] = ((unsigned)ss << 8) | ((unsigned)(g & 3) << 6) | (unsigned)dl;
            atomicAdd(&deg_out[ss], 1);
        }
    }
}

// ---------------- K3: fnorm[n][f] = bf16(feat[n][f] * rsqrt(max(deg_out,1))), 32-padded ----
__global__ void fnorm_kernel(const float* __restrict__ feat, const int* __restrict__ deg_out,
                             ushort* __restrict__ fnorm) {
    int idx = blockIdx.x * blockDim.x + threadIdx.x;
    int n = idx >> 5;
    int f = idx & 31;
    if (n >= N_NODES) return;
    float ns = rsqrtf(fmaxf((float)deg_out[n], 1.0f));
    float v = (f < IN_F) ? feat[(size_t)n * IN_F + f] * ns : 0.f;
    __hip_bfloat16 bv = __float2bfloat16(v);
    fnorm[((size_t)n << 5) + f] = *reinterpret_cast<ushort*>(&bv);
}

// ---------------- K4: fused gather-aggregate (2 graphs/block) + epilogue ----------------
// quad (4 lanes) per edge, uint4 (8 bf16) per lane; long barrier-free gather loop.
__global__ __launch_bounds__(256) void agg_pool_mlp(
    const uint4* __restrict__ fnorm4, const int* __restrict__ bin_start,
    const unsigned* __restrict__ binned,
    const float* __restrict__ W, const float* __restrict__ b,
    const float* __restrict__ W2, const float* __restrict__ b2,
    const float* __restrict__ W3, const float* __restrict__ b3,
    float* __restrict__ out) {
    int g0 = blockIdx.x * GPB;
    int t = threadIdx.x;     // 256
    int l = t & 3;           // 8-feature slice within row
    int q = t >> 2;          // edge slot 0..63
    __shared__ float acc[GPB * NPG][33];   // bank = (row + 8l + j) % 32 -> spread
    __shared__ int cntn[GPB * NPG];        // per-node in-degree counters
    __shared__ float sW[IN_F * H1];
    __shared__ unsigned sE[CAP];
    __shared__ float smax[8][32];
    __shared__ float pooled[32];
    __shared__ float z[H2];

    int beg = bin_start[g0];
    int cnt = bin_start[g0 + GPB] - beg;

    for (int i = t; i < GPB * NPG * 33; i += 256) ((float*)acc)[i] = 0.f;
    for (int i = t; i < GPB * NPG; i += 256) cntn[i] = 0;
    for (int i = t; i < IN_F * H1; i += 256) sW[i] = W[i];
    int scnt = (cnt < CAP) ? cnt : CAP;
    for (int i = t; i < scnt; i += 256) sE[i] = binned[beg + i];
    __syncthreads();

    #define EDGE_BODY(PEXPR)                                                        \
        {                                                                           \
            unsigned p = (PEXPR);                                                   \
            uint4 r = fnorm4[(size_t)(p >> 8) * 4 + l];                             \
            int row = (int)((p >> 6) & (GPB - 1)) * NPG + (int)(p & 63u);           \
            if (l == 0) atomicAdd(&cntn[row], 1);                                   \
            float* a = &acc[row][l * 8];                                            \
            const unsigned* w = reinterpret_cast<const unsigned*>(&r);              \
            _Pragma("unroll")                                                       \
            for (int j = 0; j < 8; j++) {                                           \
                unsigned u = ((w[j >> 1] >> ((j & 1) * 16)) & 0xffffu) << 16;       \
                atomicAdd(&a[j], __uint_as_float(u));                               \
            }                                                                       \
        }

    if (cnt <= CAP) {
        #pragma unroll 4
        for (int e = q; e < cnt; e += 64) EDGE_BODY(sE[e])
    } else {
        #pragma unroll 4
        for (int e = q; e < cnt; e += 64) EDGE_BODY(binned[beg + e])
    }
    #undef EDGE_BODY
    __syncthreads();

    int f = t & 31;
    int hw = t >> 5;
    #pragma unroll
    for (int gi = 0; gi < GPB; gi++) {
        float m = -INFINITY;
        for (int n = hw; n < NPG; n += 8) {
            int row = gi * NPG + n;
            float nd = rsqrtf(fmaxf((float)cntn[row], 1.0f));
            if (f < H1) {
                float s = 0.f;
                #pragma unroll
                for (int k = 0; k < IN_F; k++) s += acc[row][k] * sW[k * H1 + f];
                m = fmaxf(m, s * nd + b[f]);
            }
        }
        smax[hw][f] = m;
        __syncthreads();
        if (t < 32) {
            float mm = smax[0][t];
            #pragma unroll
            for (int k = 1; k < 8; k++) mm = fmaxf(mm, smax[k][t]);
            pooled[t] = mm;
        }
        __syncthreads();
        if (t < H2) {
            float s2 = b2[t];
            #pragma unroll
            for (int k = 0; k < H1; k++) s2 += pooled[k] * W2[k * H2 + t];
            z[t] = fmaxf(s2, 0.f);
        }
        __syncthreads();
        if (t < OUTF) {
            float s3 = b3[t];
            #pragma unroll
            for (int k = 0; k < H2; k++) s3 += z[k] * W3[k * OUTF + t];
            out[(g0 + gi) * OUTF + t] = 1.f / (1.f + expf(-s3));
        }
        __syncthreads();
    }
}

extern "C" void kernel_launch(void* const* d_in, const int* in_sizes, int n_in,
                              void* d_out, int out_size, void* d_ws, size_t ws_size,
                              hipStream_t stream) {
    const float* feat = (const float*)d_in[0];
    const int*   src  = (const int*)d_in[1];
    const int*   dst  = (const int*)d_in[2];
    const float* W  = (const float*)d_in[5];
    const float* b  = (const float*)d_in[6];
    const float* W2 = (const float*)d_in[7];
    const float* b2 = (const float*)d_in[8];
    const float* W3 = (const float*)d_in[9];
    const float* b3 = (const float*)d_in[10];
    float* out = (float*)d_out;

    char* ws = (char*)d_ws;
    int* deg_out   = (int*)ws;                       // 400000
    int* gsum      = deg_out + N_NODES;              // 10240 (zeroed with deg_out)
    int* bin_start = gsum + 10240;                   // 10304 (incl sentinel)
    int* gcursor   = bin_start + 10304;              // 10240
    int* blk_sums  = gcursor + 10240;                // 64
    int* blk_off   = blk_sums + 64;                  // 64
    unsigned* binned = (unsigned*)(blk_off + 64);    // 2400000
    ushort* fnorm  = (ushort*)(binned + N_EDGES);    // 400000*32 bf16, 64B-aligned

    hipMemsetAsync(deg_out, 0, sizeof(int) * (N_NODES + 10240), stream);

    hist_kernel<<<2048, 256, 0, stream>>>((const int4*)dst, gsum);

    scan1<<<SCAN_NB, 256, 0, stream>>>(gsum, bin_start, blk_sums, N_GRAPHS);
    scan2<<<1, 64, 0, stream>>>(blk_sums, blk_off, SCAN_NB);
    scan3<<<SCAN_NB, 256, 0, stream>>>(bin_start, gcursor, blk_off, gsum, N_GRAPHS);

    bin_fill<<<2048, 256, 0, stream>>>((const int4*)src, (const int4*)dst,
                                       gcursor, binned, deg_out);

    fnorm_kernel<<<(N_NODES * 32 + 255) / 256, 256, 0, stream>>>(feat, deg_out, fnorm);

    agg_pool_mlp<<<NBLK, 256, 0, stream>>>((const uint4*)fnorm, bin_start, binned,
                                           W, b, W2, b2, W3, b3, out);
}

// Round 7
// 509.220 us; speedup vs baseline: 1.7037x; 1.7037x over previous
//
#include <hip/hip_runtime.h>
#include <hip/hip_bf16.h>
#include <math.h>

#define N_NODES 400000
#define N_EDGES 2400000
#define NPG 40
#define N_GRAPHS 10000
#define IN_F 30
#define H1 30
#define H2 10
#define OUTF 4
#define SCAN_NB 10      // ceil(10000/1024)
#define GPB 2           // graphs per block in fused kernel
#define NBLK (N_GRAPHS / GPB)
#define ROWS (GPB * NPG)  // 80 dst nodes per block
#define CAP 768         // LDS edge staging cap; cnt ~ Poisson(480), 768 = +13 sigma

// ---------------- K1: per-graph edge histogram ----------------
__global__ void hist_kernel(const int4* __restrict__ dst4, int* __restrict__ gsum) {
    int i = blockIdx.x * blockDim.x + threadIdx.x;
    int stride = gridDim.x * blockDim.x;
    const int n4 = N_EDGES / 4;
    for (; i < n4; i += stride) {
        int4 d = dst4[i];
        atomicAdd(&gsum[d.x / NPG], 1);
        atomicAdd(&gsum[d.y / NPG], 1);
        atomicAdd(&gsum[d.z / NPG], 1);
        atomicAdd(&gsum[d.w / NPG], 1);
    }
}

// ---------------- exclusive scan of gsum -> bin_start (+sentinel), gcursor ----------------
__global__ void scan1(const int* __restrict__ v_in, int* __restrict__ ex_out,
                      int* __restrict__ blk_sums, int n) {
    __shared__ int s[256];
    int t = threadIdx.x;
    int base = blockIdx.x * 1024 + t * 4;
    int v[4];
    #pragma unroll
    for (int k = 0; k < 4; k++) v[k] = (base + k < n) ? v_in[base + k] : 0;
    int tsum = v[0] + v[1] + v[2] + v[3];
    s[t] = tsum;
    __syncthreads();
    for (int o = 1; o < 256; o <<= 1) {
        int y = (t >= o) ? s[t - o] : 0;
        __syncthreads();
        s[t] += y;
        __syncthreads();
    }
    int run = s[t] - tsum;
    #pragma unroll
    for (int k = 0; k < 4; k++) {
        if (base + k < n) ex_out[base + k] = run;
        run += v[k];
    }
    if (t == 255) blk_sums[blockIdx.x] = s[255];
}

__global__ void scan2(const int* __restrict__ blk_sums, int* __restrict__ blk_off, int nb) {
    if (threadIdx.x == 0) {
        int run = 0;
        for (int i = 0; i < nb; i++) { blk_off[i] = run; run += blk_sums[i]; }
    }
}

__global__ void scan3(int* __restrict__ bin_start, int* __restrict__ gcursor,
                      const int* __restrict__ blk_off, const int* __restrict__ gsum, int n) {
    int t = threadIdx.x;
    int off = blk_off[blockIdx.x];
    int base = blockIdx.x * 1024 + t * 4;
    #pragma unroll
    for (int k = 0; k < 4; k++) {
        int i = base + k;
        if (i < n) {
            int r = bin_start[i] + off;
            bin_start[i] = r;
            gcursor[i] = r;
            if (i == n - 1) bin_start[n] = r + gsum[i];  // sentinel = N_EDGES
        }
    }
}

// ---------------- K2: bin edges by dst graph; also out-degree histogram ----------------
// packed word: (src << 8) | ((g & 3) << 6) | dst_local   (src < 2^19)
__global__ void bin_fill(const int4* __restrict__ src4, const int4* __restrict__ dst4,
                         int* __restrict__ gcursor, unsigned* __restrict__ binned,
                         int* __restrict__ deg_out) {
    int i = blockIdx.x * blockDim.x + threadIdx.x;
    int stride = gridDim.x * blockDim.x;
    const int n4 = N_EDGES / 4;
    for (; i < n4; i += stride) {
        int4 s = src4[i];
        int4 d = dst4[i];
        #pragma unroll
        for (int k = 0; k < 4; k++) {
            int dd = (k == 0) ? d.x : (k == 1) ? d.y : (k == 2) ? d.z : d.w;
            int ss = (k == 0) ? s.x : (k == 1) ? s.y : (k == 2) ? s.z : s.w;
            int g = dd / NPG;
            int dl = dd - g * NPG;
            int pos = atomicAdd(&gcursor[g], 1);
            binned[pos] = ((unsigned)ss << 8) | ((unsigned)(g & 3) << 6) | (unsigned)dl;
            atomicAdd(&deg_out[ss], 1);
        }
    }
}

// ---------------- K3: fnorm[n][f] = bf16(feat[n][f] * rsqrt(max(deg_out,1))), 32-padded ----
__global__ void fnorm_kernel(const float* __restrict__ feat, const int* __restrict__ deg_out,
                             ushort* __restrict__ fnorm) {
    int idx = blockIdx.x * blockDim.x + threadIdx.x;
    int n = idx >> 5;
    int f = idx & 31;
    if (n >= N_NODES) return;
    float ns = rsqrtf(fmaxf((float)deg_out[n], 1.0f));
    float v = (f < IN_F) ? feat[(size_t)n * IN_F + f] * ns : 0.f;
    __hip_bfloat16 bv = __float2bfloat16(v);
    fnorm[((size_t)n << 5) + f] = *reinterpret_cast<ushort*>(&bv);
}

// ---------------- K4: fused: in-LDS counting sort by dst node -> register-accum gather ----
// quad (4 lanes x 16B) per dst-node; NO LDS ops in the gather loop.
__global__ __launch_bounds__(256) void agg_pool_mlp(
    const uint4* __restrict__ fnorm4, const int* __restrict__ bin_start,
    const unsigned* __restrict__ binned,
    const float* __restrict__ W, const float* __restrict__ b,
    const float* __restrict__ W2, const float* __restrict__ b2,
    const float* __restrict__ W3, const float* __restrict__ b3,
    float* __restrict__ out) {
    int g0 = blockIdx.x * GPB;
    int t = threadIdx.x;     // 256
    int l = t & 3;           // 8-feature (16B) slice within the 64B row
    int q = t >> 2;          // quad id 0..63
    __shared__ unsigned sE[CAP];        // staged packed edges
    __shared__ unsigned sS[CAP];        // src ids sorted by dst row
    __shared__ int cnt_n[ROWS];         // per-node in-degree
    __shared__ int start_n[ROWS];       // per-node start in sS
    __shared__ int cur_n[ROWS];         // scatter cursors
    __shared__ int scan_s[128];
    __shared__ float sAcc[ROWS][33];
    __shared__ float sW[IN_F * H1];
    __shared__ float smax[8][32];
    __shared__ float pooled[32];
    __shared__ float z[H2];

    int beg = bin_start[g0];
    int cnt = bin_start[g0 + GPB] - beg;

    for (int i = t; i < ROWS; i += 256) cnt_n[i] = 0;
    for (int i = t; i < IN_F * H1; i += 256) sW[i] = W[i];
    int scnt = (cnt < CAP) ? cnt : CAP;
    for (int i = t; i < scnt; i += 256) sE[i] = binned[beg + i];
    __syncthreads();

    // histogram by dst row
    for (int i = t; i < cnt; i += 256) {
        unsigned p = (i < CAP) ? sE[i] : binned[beg + i];
        int row = (int)((p >> 6) & (GPB - 1)) * NPG + (int)(p & 63u);
        atomicAdd(&cnt_n[row], 1);
    }
    __syncthreads();

    // exclusive scan over ROWS (Hillis-Steele on 128 slots)
    if (t < 128) scan_s[t] = (t < ROWS) ? cnt_n[t] : 0;
    __syncthreads();
    for (int o = 1; o < 128; o <<= 1) {
        int y = 0;
        if (t < 128 && t >= o) y = scan_s[t - o];
        __syncthreads();
        if (t < 128) scan_s[t] += y;
        __syncthreads();
    }
    if (t < ROWS) {
        int ex = scan_s[t] - cnt_n[t];
        start_n[t] = ex;
        cur_n[t] = ex;
    }
    __syncthreads();

    // counting-sort scatter: sS[pos] = src id, grouped by dst row
    if (cnt <= CAP) {
        for (int i = t; i < cnt; i += 256) {
            unsigned p = sE[i];
            int row = (int)((p >> 6) & (GPB - 1)) * NPG + (int)(p & 63u);
            int pos = atomicAdd(&cur_n[row], 1);
            sS[pos] = p >> 8;
        }
    }
    __syncthreads();

    // gather: quad per dst node, register accumulation, no LDS in loop
    for (int nn = q; nn < ROWS; nn += 64) {
        float a[8];
        #pragma unroll
        for (int j = 0; j < 8; j++) a[j] = 0.f;
        int st = start_n[nn];
        int dg = cnt_n[nn];
        if (cnt <= CAP) {
            for (int j = 0; j < dg; ++j) {
                unsigned id = sS[st + j];
                uint4 r = fnorm4[(size_t)id * 4 + l];
                const unsigned* w = reinterpret_cast<const unsigned*>(&r);
                #pragma unroll
                for (int k = 0; k < 4; k++) {
                    a[2 * k]     += __uint_as_float(w[k] << 16);
                    a[2 * k + 1] += __uint_as_float(w[k] & 0xffff0000u);
                }
            }
        } else {
            // overflow fallback (never taken for this input): scan all edges
            for (int e = 0; e < cnt; ++e) {
                unsigned p = binned[beg + e];
                int row = (int)((p >> 6) & (GPB - 1)) * NPG + (int)(p & 63u);
                if (row == nn) {
                    uint4 r = fnorm4[(size_t)(p >> 8) * 4 + l];
                    const unsigned* w = reinterpret_cast<const unsigned*>(&r);
                    #pragma unroll
                    for (int k = 0; k < 4; k++) {
                        a[2 * k]     += __uint_as_float(w[k] << 16);
                        a[2 * k + 1] += __uint_as_float(w[k] & 0xffff0000u);
                    }
                }
            }
        }
        #pragma unroll
        for (int j = 0; j < 8; j++) sAcc[nn][l * 8 + j] = a[j];
    }
    __syncthreads();

    // epilogue: @W * nd + b -> per-graph max -> MLP -> sigmoid
    int f = t & 31;
    int hw = t >> 5;
    #pragma unroll
    for (int gi = 0; gi < GPB; gi++) {
        float m = -INFINITY;
        for (int n = hw; n < NPG; n += 8) {
            int row = gi * NPG + n;
            float nd = rsqrtf(fmaxf((float)cnt_n[row], 1.0f));
            if (f < H1) {
                float s = 0.f;
                #pragma unroll
                for (int k = 0; k < IN_F; k++) s += sAcc[row][k] * sW[k * H1 + f];
                m = fmaxf(m, s * nd + b[f]);
            }
        }
        smax[hw][f] = m;
        __syncthreads();
        if (t < 32) {
            float mm = smax[0][t];
            #pragma unroll
            for (int k = 1; k < 8; k++) mm = fmaxf(mm, smax[k][t]);
            pooled[t] = mm;
        }
        __syncthreads();
        if (t < H2) {
            float s2 = b2[t];
            #pragma unroll
            for (int k = 0; k < H1; k++) s2 += pooled[k] * W2[k * H2 + t];
            z[t] = fmaxf(s2, 0.f);
        }
        __syncthreads();
        if (t < OUTF) {
            float s3 = b3[t];
            #pragma unroll
            for (int k = 0; k < H2; k++) s3 += z[k] * W3[k * OUTF + t];
            out[(g0 + gi) * OUTF + t] = 1.f / (1.f + expf(-s3));
        }
        __syncthreads();
    }
}

extern "C" void kernel_launch(void* const* d_in, const int* in_sizes, int n_in,
                              void* d_out, int out_size, void* d_ws, size_t ws_size,
                              hipStream_t stream) {
    const float* feat = (const float*)d_in[0];
    const int*   src  = (const int*)d_in[1];
    const int*   dst  = (const int*)d_in[2];
    const float* W  = (const float*)d_in[5];
    const float* b  = (const float*)d_in[6];
    const float* W2 = (const float*)d_in[7];
    const float* b2 = (const float*)d_in[8];
    const float* W3 = (const float*)d_in[9];
    const float* b3 = (const float*)d_in[10];
    float* out = (float*)d_out;

    char* ws = (char*)d_ws;
    int* deg_out   = (int*)ws;                       // 400000
    int* gsum      = deg_out + N_NODES;              // 10240 (zeroed with deg_out)
    int* bin_start = gsum + 10240;                   // 10304 (incl sentinel)
    int* gcursor   = bin_start + 10304;              // 10240
    int* blk_sums  = gcursor + 10240;                // 64
    int* blk_off   = blk_sums + 64;                  // 64
    unsigned* binned = (unsigned*)(blk_off + 64);    // 2400000
    ushort* fnorm  = (ushort*)(binned + N_EDGES);    // 400000*32 bf16, 64B-aligned

    hipMemsetAsync(deg_out, 0, sizeof(int) * (N_NODES + 10240), stream);

    hist_kernel<<<2048, 256, 0, stream>>>((const int4*)dst, gsum);

    scan1<<<SCAN_NB, 256, 0, stream>>>(gsum, bin_start, blk_sums, N_GRAPHS);
    scan2<<<1, 64, 0, stream>>>(blk_sums, blk_off, SCAN_NB);
    scan3<<<SCAN_NB, 256, 0, stream>>>(bin_start, gcursor, blk_off, gsum, N_GRAPHS);

    bin_fill<<<2048, 256, 0, stream>>>((const int4*)src, (const int4*)dst,
                                       gcursor, binned, deg_out);

    fnorm_kernel<<<(N_NODES * 32 + 255) / 256, 256, 0, stream>>>(feat, deg_out, fnorm);

    agg_pool_mlp<<<NBLK, 256, 0, stream>>>((const uint4*)fnorm, bin_start, binned,
                                           W, b, W2, b2, W3, b3, out);
}

// Round 8
// 351.439 us; speedup vs baseline: 2.4686x; 1.4490x over previous
//
#include <hip/hip_runtime.h>
#include <hip/hip_bf16.h>
#include <math.h>

#define N_NODES 400000
#define N_EDGES 2400000
#define NPG 40
#define N_GRAPHS 10000
#define IN_F 30
#define H1 30
#define H2 10
#define OUTF 4
#define GPB 2             // graphs per fused block
#define NBLK (N_GRAPHS / GPB)
#define ROWS (GPB * NPG)  // 80 dst nodes per fused block
#define CAP 1024          // staged edges cap; per-block ~Binom mean 480 sd 22 -> +24 sigma
#define NBUCK 625         // 16 graphs per bucket
#define SORTB 256         // sort grid blocks (must match S1/S3)

// ---------------- S1: per-(bucket,block) histogram + out-degree ----------------
__global__ void sort_hist(const int4* __restrict__ src4, const int4* __restrict__ dst4,
                          int* __restrict__ bkblk, int* __restrict__ deg_out) {
    __shared__ int h[NBUCK];
    for (int i = threadIdx.x; i < NBUCK; i += 256) h[i] = 0;
    __syncthreads();
    int i = blockIdx.x * 256 + threadIdx.x;
    int stride = gridDim.x * 256;
    const int n4 = N_EDGES / 4;
    for (; i < n4; i += stride) {
        int4 d = dst4[i];
        int4 s = src4[i];
        atomicAdd(&h[d.x / 640], 1);  atomicAdd(&h[d.y / 640], 1);
        atomicAdd(&h[d.z / 640], 1);  atomicAdd(&h[d.w / 640], 1);
        atomicAdd(&deg_out[s.x], 1);  atomicAdd(&deg_out[s.y], 1);
        atomicAdd(&deg_out[s.z], 1);  atomicAdd(&deg_out[s.w], 1);
    }
    __syncthreads();
    for (int j = threadIdx.x; j < NBUCK; j += 256) bkblk[j * SORTB + blockIdx.x] = h[j];
}

// ---------------- S2: offsets: off[bu][blk] = global base for that segment ----------------
__global__ void sort_scan(const int* __restrict__ bkblk, int* __restrict__ off,
                          int* __restrict__ bk_start) {
    __shared__ int s[1024];
    int t = threadIdx.x;
    int total = 0;
    if (t < NBUCK) {
        int run = 0;
        for (int b2 = 0; b2 < SORTB; b2++) { off[t * SORTB + b2] = run; run += bkblk[t * SORTB + b2]; }
        total = run;
    }
    s[t] = total;
    __syncthreads();
    for (int o = 1; o < 1024; o <<= 1) {
        int y = (t >= o) ? s[t - o] : 0;
        __syncthreads();
        s[t] += y;
        __syncthreads();
    }
    int base = s[t] - total;   // exclusive prefix across buckets
    if (t < NBUCK) {
        bk_start[t] = base;
        for (int b2 = 0; b2 < SORTB; b2++) off[t * SORTB + b2] += base;
        if (t == NBUCK - 1) bk_start[NBUCK] = base + total;
    }
}

// ---------------- S3: scatter into bucket segments (coalesced-in-time writes) ------------
// packed word: (src << 10) | ((g & 15) << 6) | dst_local
__global__ void sort_scatter(const int4* __restrict__ src4, const int4* __restrict__ dst4,
                             const int* __restrict__ off, unsigned* __restrict__ binned) {
    __shared__ int cur[NBUCK];
    for (int i = threadIdx.x; i < NBUCK; i += 256) cur[i] = off[i * SORTB + blockIdx.x];
    __syncthreads();
    int i = blockIdx.x * 256 + threadIdx.x;
    int stride = gridDim.x * 256;
    const int n4 = N_EDGES / 4;
    for (; i < n4; i += stride) {
        int4 d = dst4[i];
        int4 s = src4[i];
        #pragma unroll
        for (int k = 0; k < 4; k++) {
            int dd = (k == 0) ? d.x : (k == 1) ? d.y : (k == 2) ? d.z : d.w;
            int ss = (k == 0) ? s.x : (k == 1) ? s.y : (k == 2) ? s.z : s.w;
            int g = dd / NPG;
            int dl = dd - g * NPG;
            int bu = g >> 4;
            int pos = atomicAdd(&cur[bu], 1);
            binned[pos] = ((unsigned)ss << 10) | ((unsigned)(g & 15) << 6) | (unsigned)dl;
        }
    }
}

// ---------------- K3: fnorm[n][f] = bf16(feat[n][f] * rsqrt(max(deg_out,1))), 32-padded ----
__global__ void fnorm_kernel(const float* __restrict__ feat, const int* __restrict__ deg_out,
                             ushort* __restrict__ fnorm) {
    int idx = blockIdx.x * blockDim.x + threadIdx.x;
    int n = idx >> 5;
    int f = idx & 31;
    if (n >= N_NODES) return;
    float ns = rsqrtf(fmaxf((float)deg_out[n], 1.0f));
    float v = (f < IN_F) ? feat[(size_t)n * IN_F + f] * ns : 0.f;
    __hip_bfloat16 bv = __float2bfloat16(v);
    fnorm[((size_t)n << 5) + f] = *reinterpret_cast<ushort*>(&bv);
}

// ---------------- K4: fused: bucket-scan stage -> LDS counting sort -> register gather ----
__global__ __launch_bounds__(256) void agg_pool_mlp(
    const uint4* __restrict__ fnorm4, const int* __restrict__ bk_start,
    const unsigned* __restrict__ binned,
    const float* __restrict__ W, const float* __restrict__ b,
    const float* __restrict__ W2, const float* __restrict__ b2,
    const float* __restrict__ W3, const float* __restrict__ b3,
    float* __restrict__ out) {
    int g0 = blockIdx.x * GPB;
    int t = threadIdx.x;     // 256
    int l = t & 3;           // 16B slice of the 64B fnorm row
    int q = t >> 2;          // quad id 0..63
    __shared__ unsigned sE[CAP];     // staged (src<<7)|row
    __shared__ unsigned sS[CAP];     // src ids grouped by row
    __shared__ int cnt_n[ROWS];      // per-row staged count (sort sizes)
    __shared__ int deg_x[ROWS];      // fallback-path extra degree
    __shared__ int start_n[ROWS];
    __shared__ int cur_n[ROWS];
    __shared__ int scan_s[128];
    __shared__ int scount;
    __shared__ float sAcc[ROWS][33];
    __shared__ float sW[IN_F * H1];
    __shared__ float smax[8][32];
    __shared__ float pooled[32];
    __shared__ float z[H2];

    for (int i = t; i < ROWS; i += 256) { cnt_n[i] = 0; deg_x[i] = 0; }
    for (int i = t; i < ROWS * 33; i += 256) ((float*)sAcc)[i] = 0.f;
    for (int i = t; i < IN_F * H1; i += 256) sW[i] = W[i];
    if (t == 0) scount = 0;
    __syncthreads();

    // stage this block's edges out of the 16-graph bucket
    int bu = g0 >> 4;
    int ebeg = bk_start[bu], eend = bk_start[bu + 1];
    unsigned want = (unsigned)((g0 & 15) >> 1);
    for (int i = ebeg + t; i < eend; i += 256) {
        unsigned p = binned[i];
        if (((p >> 7) & 7u) == want) {
            int row = (int)((p >> 6) & 1u) * NPG + (int)(p & 63u);
            int pos = atomicAdd(&scount, 1);
            if (pos < CAP) {
                sE[pos] = ((p >> 10) << 7) | (unsigned)row;
            } else {
                // overflow fallback (probabilistically never): accumulate directly
                atomicAdd(&deg_x[row], 1);
                const unsigned* fr = reinterpret_cast<const unsigned*>(
                    &fnorm4[(size_t)(p >> 10) * 4]);
                for (int k = 0; k < 16; k++) {
                    unsigned wv = fr[k];
                    atomicAdd(&sAcc[row][2 * k],     __uint_as_float(wv << 16));
                    atomicAdd(&sAcc[row][2 * k + 1], __uint_as_float(wv & 0xffff0000u));
                }
            }
        }
    }
    __syncthreads();
    int cnt = (scount < CAP) ? scount : CAP;

    // histogram staged edges by row
    for (int i = t; i < cnt; i += 256) atomicAdd(&cnt_n[sE[i] & 127u], 1);
    __syncthreads();

    // exclusive scan over ROWS (Hillis-Steele, 128 wide)
    if (t < 128) scan_s[t] = (t < ROWS) ? cnt_n[t] : 0;
    __syncthreads();
    for (int o = 1; o < 128; o <<= 1) {
        int y = 0;
        if (t < 128 && t >= o) y = scan_s[t - o];
        __syncthreads();
        if (t < 128) scan_s[t] += y;
        __syncthreads();
    }
    if (t < ROWS) {
        int ex = scan_s[t] - cnt_n[t];
        start_n[t] = ex;
        cur_n[t] = ex;
    }
    __syncthreads();

    // counting-sort scatter: sS grouped by row
    for (int i = t; i < cnt; i += 256) {
        unsigned e = sE[i];
        int row = (int)(e & 127u);
        int pos = atomicAdd(&cur_n[row], 1);
        sS[pos] = e >> 7;
    }
    __syncthreads();

    // gather: quad per dst row, register accumulation, no LDS ops in loop
    for (int nn = q; nn < ROWS; nn += 64) {
        float a[8];
        #pragma unroll
        for (int j = 0; j < 8; j++) a[j] = 0.f;
        int st = start_n[nn];
        int dg = cnt_n[nn];
        for (int j = 0; j < dg; ++j) {
            unsigned id = sS[st + j];
            uint4 r = fnorm4[(size_t)id * 4 + l];
            const unsigned* w = reinterpret_cast<const unsigned*>(&r);
            #pragma unroll
            for (int k = 0; k < 4; k++) {
                a[2 * k]     += __uint_as_float(w[k] << 16);
                a[2 * k + 1] += __uint_as_float(w[k] & 0xffff0000u);
            }
        }
        #pragma unroll
        for (int j = 0; j < 8; j++) sAcc[nn][l * 8 + j] += a[j];
    }
    __syncthreads();

    // epilogue: @W * nd + b -> per-graph max -> MLP -> sigmoid
    int f = t & 31;
    int hw = t >> 5;
    #pragma unroll
    for (int gi = 0; gi < GPB; gi++) {
        float m = -INFINITY;
        for (int n = hw; n < NPG; n += 8) {
            int row = gi * NPG + n;
            float nd = rsqrtf(fmaxf((float)(cnt_n[row] + deg_x[row]), 1.0f));
            if (f < H1) {
                float s = 0.f;
                #pragma unroll
                for (int k = 0; k < IN_F; k++) s += sAcc[row][k] * sW[k * H1 + f];
                m = fmaxf(m, s * nd + b[f]);
            }
        }
        smax[hw][f] = m;
        __syncthreads();
        if (t < 32) {
            float mm = smax[0][t];
            #pragma unroll
            for (int k = 1; k < 8; k++) mm = fmaxf(mm, smax[k][t]);
            pooled[t] = mm;
        }
        __syncthreads();
        if (t < H2) {
            float s2 = b2[t];
            #pragma unroll
            for (int k = 0; k < H1; k++) s2 += pooled[k] * W2[k * H2 + t];
            z[t] = fmaxf(s2, 0.f);
        }
        __syncthreads();
        if (t < OUTF) {
            float s3 = b3[t];
            #pragma unroll
            for (int k = 0; k < H2; k++) s3 += z[k] * W3[k * OUTF + t];
            out[(g0 + gi) * OUTF + t] = 1.f / (1.f + expf(-s3));
        }
        __syncthreads();
    }
}

extern "C" void kernel_launch(void* const* d_in, const int* in_sizes, int n_in,
                              void* d_out, int out_size, void* d_ws, size_t ws_size,
                              hipStream_t stream) {
    const float* feat = (const float*)d_in[0];
    const int*   src  = (const int*)d_in[1];
    const int*   dst  = (const int*)d_in[2];
    const float* W  = (const float*)d_in[5];
    const float* b  = (const float*)d_in[6];
    const float* W2 = (const float*)d_in[7];
    const float* b2 = (const float*)d_in[8];
    const float* W3 = (const float*)d_in[9];
    const float* b3 = (const float*)d_in[10];
    float* out = (float*)d_out;

    char* ws = (char*)d_ws;
    int* deg_out  = (int*)ws;                        // 400000 (zeroed)
    int* bkblk    = deg_out + N_NODES;               // 625*256 = 160000
    int* off      = bkblk + NBUCK * SORTB;           // 160000
    int* bk_start = off + NBUCK * SORTB;             // 626 (pad to 640)
    unsigned* binned = (unsigned*)(bk_start + 640);  // 2400000 (64B-aligned)
    ushort* fnorm = (ushort*)(binned + N_EDGES);     // 400000*32 bf16 = 25.6MB

    hipMemsetAsync(deg_out, 0, sizeof(int) * N_NODES, stream);

    sort_hist<<<SORTB, 256, 0, stream>>>((const int4*)src, (const int4*)dst,
                                         bkblk, deg_out);
    sort_scan<<<1, 1024, 0, stream>>>(bkblk, off, bk_start);
    sort_scatter<<<SORTB, 256, 0, stream>>>((const int4*)src, (const int4*)dst,
                                            off, binned);

    fnorm_kernel<<<(N_NODES * 32 + 255) / 256, 256, 0, stream>>>(feat, deg_out, fnorm);

    agg_pool_mlp<<<NBLK, 256, 0, stream>>>((const uint4*)fnorm, bk_start, binned,
                                           W, b, W2, b2, W3, b3, out);
}